// Round 4
// baseline (100.733 us; speedup 1.0000x reference)
//
#include <hip/hip_runtime.h>

#define DIMV 16
#define NSTEP 4095      // 4096 - 1 increments
#define NC 128          // chunks
#define TSTEP 32        // ceil(NSTEP / NC)
#define SIG13 4368      // 16 + 256 + 4096
#define L4 65536        // 16^4

// 16-wide register vector as 4 explicit float4s — never runtime-indexed (rule #20).
struct V16 { float4 a, b, c, d; };

#define EACH(OP) OP(a,x) OP(a,y) OP(a,z) OP(a,w) OP(b,x) OP(b,y) OP(b,z) OP(b,w) \
                 OP(c,x) OP(c,y) OP(c,z) OP(c,w) OP(d,x) OP(d,y) OP(d,z) OP(d,w)
#define EACHI(OP) OP(0,a,x) OP(1,a,y) OP(2,a,z) OP(3,a,w) \
                  OP(4,b,x) OP(5,b,y) OP(6,b,z) OP(7,b,w) \
                  OP(8,c,x) OP(9,c,y) OP(10,c,z) OP(11,c,w) \
                  OP(12,d,x) OP(13,d,y) OP(14,d,z) OP(15,d,w)

__device__ inline V16 ldv16(const float* p) {
    const float4* q = reinterpret_cast<const float4*>(p);
    V16 v; v.a = q[0]; v.b = q[1]; v.c = q[2]; v.d = q[3]; return v;
}
__device__ inline void stv16(float* p, const V16& v) {
    float4* q = reinterpret_cast<float4*>(p);
    q[0] = v.a; q[1] = v.b; q[2] = v.c; q[3] = v.d;
}
__device__ inline V16 zerov16() {
    V16 v; v.a = v.b = v.c = v.d = make_float4(0.f, 0.f, 0.f, 0.f); return v;
}

// ------------- per-chunk LOCAL signature, levels 1-3, from zero -------------
// dx fused: reads x, keeps previous row in registers, writes dx rows for k_scan4.
__global__ __launch_bounds__(256, 1) void k_chunk_sig(const float* __restrict__ x,
                                                      float* __restrict__ dx,
                                                      float* __restrict__ chunk_sig) {
    const int cb = blockIdx.x;
    const int t = threadIdx.x;
    const int ia = t >> 4, ib = t & 15;
    float A1a = 0.f, A2 = 0.f;
    V16 A3 = zerov16();

    const int s0 = cb * TSTEP;
    const int s1 = (s0 + TSTEP < NSTEP) ? (s0 + TSTEP) : NSTEP;

    V16 xprev = ldv16(x + (size_t)s0 * DIMV);
    float xpa = x[(size_t)s0 * DIMV + ia];
    float xpb = x[(size_t)s0 * DIMV + ib];

    for (int s = s0; s < s1; ++s) {
        const float* nrow = x + (size_t)(s + 1) * DIMV;
        V16 xcur = ldv16(nrow);
        float xca = nrow[ia];
        float xcb = nrow[ib];
        V16 dxv;
#define SB(Q,C) dxv.Q.C = xcur.Q.C - xprev.Q.C;
        EACH(SB)
#undef SB
        float dxa = xca - xpa;
        float dxb = xcb - xpb;
        stv16(dx + (size_t)s * DIMV, dxv);

        float V2 = fmaf(dxb, fmaf(dxa, 1.f/6.f, 0.5f * A1a), A2);
        float h2 = fmaf(dxa, 0.5f, A1a);
#define CS(Q,C) A3.Q.C = fmaf(dxv.Q.C, V2, A3.Q.C);
        EACH(CS)
#undef CS
        A2 = fmaf(dxb, h2, A2);
        A1a += dxa;

        xprev = xcur; xpa = xca; xpb = xcb;
    }
    float* o = chunk_sig + (size_t)cb * SIG13;
    if (ib == 0) o[ia] = A1a;
    o[16 + t] = A2;
    stv16(o + 272 + t * 16, A3);
}

// ------------- parallel cascaded prefix: levels 1 & 2 -------------
__global__ __launch_bounds__(256, 1) void k_prefix12(const float* __restrict__ chunk_sig,
                                                     float* __restrict__ prefix_sig,
                                                     float* __restrict__ out13) {
    __shared__ float s1[NC][16];
    __shared__ float p1[NC][16];
    const int t = threadIdx.x;
#pragma unroll
    for (int base = 0; base < NC; base += 16) {
        int c = base + (t >> 4);
        s1[c][t & 15] = chunk_sig[(size_t)c * SIG13 + (t & 15)];
    }
    __syncthreads();
    if (t < 16) {
        float p = 0.f;
        for (int c = 0; c < NC; ++c) {
            p1[c][t] = p;
            prefix_sig[(size_t)c * SIG13 + t] = p;
            p += s1[c][t];
        }
        out13[t] = p;
    }
    __syncthreads();
    const int a = t >> 4, b = t & 15;
    float pl0 = chunk_sig[0ul * SIG13 + 16 + t];
    float pl1 = chunk_sig[1ul * SIG13 + 16 + t];
    float pl2 = chunk_sig[2ul * SIG13 + 16 + t];
    float pl3 = chunk_sig[3ul * SIG13 + 16 + t];
    float pl4 = chunk_sig[4ul * SIG13 + 16 + t];
    float pl5 = chunk_sig[5ul * SIG13 + 16 + t];
    float pl6 = chunk_sig[6ul * SIG13 + 16 + t];
    float pl7 = chunk_sig[7ul * SIG13 + 16 + t];
    float p = 0.f;
    for (int cb = 0; cb < NC; cb += 8) {
#define STEP2(J) { int c = cb + J; \
        prefix_sig[(size_t)c * SIG13 + 16 + t] = p; \
        p = fmaf(p1[c][a], s1[c][b], p + pl##J); \
        int cn = c + 8; \
        if (cn < NC) pl##J = chunk_sig[(size_t)cn * SIG13 + 16 + t]; }
        STEP2(0) STEP2(1) STEP2(2) STEP2(3) STEP2(4) STEP2(5) STEP2(6) STEP2(7)
#undef STEP2
    }
    out13[16 + t] = p;
}

// ------------- parallel prefix: level 3 -------------
__global__ __launch_bounds__(256, 1) void k_prefix3(const float* __restrict__ chunk_sig,
                                                    float* __restrict__ prefix_sig,
                                                    float* __restrict__ out13) {
    const int a = blockIdx.x;
    const int t = threadIdx.x;
    const int c3 = t & 15;
    const size_t off3 = 272 + (size_t)a * 256 + t;
#define LOADC(J, C) \
    float l3_##J = chunk_sig[(size_t)(C) * SIG13 + off3]; \
    float l2_##J = chunk_sig[(size_t)(C) * SIG13 + 16 + t]; \
    float s1_##J = chunk_sig[(size_t)(C) * SIG13 + c3]; \
    float pa_##J = prefix_sig[(size_t)(C) * SIG13 + a]; \
    float pb_##J = prefix_sig[(size_t)(C) * SIG13 + 16 + (a << 4) + (t >> 4)];
#define RELOADC(J, C) { int cc = (C); if (cc < NC) { \
    l3_##J = chunk_sig[(size_t)cc * SIG13 + off3]; \
    l2_##J = chunk_sig[(size_t)cc * SIG13 + 16 + t]; \
    s1_##J = chunk_sig[(size_t)cc * SIG13 + c3]; \
    pa_##J = prefix_sig[(size_t)cc * SIG13 + a]; \
    pb_##J = prefix_sig[(size_t)cc * SIG13 + 16 + (a << 4) + (t >> 4)]; } }
    LOADC(0, 0) LOADC(1, 1) LOADC(2, 2) LOADC(3, 3)
    float p = 0.f;
    for (int cb = 0; cb < NC; cb += 4) {
#define STEP3(J) { int c = cb + J; \
        prefix_sig[(size_t)c * SIG13 + off3] = p; \
        p = p + l3_##J + fmaf(pa_##J, l2_##J, pb_##J * s1_##J); \
        RELOADC(J, c + 4) }
        STEP3(0) STEP3(1) STEP3(2) STEP3(3)
#undef STEP3
    }
    out13[off3] = p;
#undef LOADC
#undef RELOADC
}

// ------------- level-4 accumulation: re-scan chunk from true prefix -------------
template <bool ATOMIC>
__global__ __launch_bounds__(256, 2) void k_scan4(const float* __restrict__ dx,
                                                  const float* __restrict__ prefix_sig,
                                                  float* __restrict__ dst) {
    const int cb = blockIdx.x;
    const int g = blockIdx.y;   // 0..3 : d-group
    const int t = threadIdx.x;
    const int ia = t >> 4, ib = t & 15;

    const float* P = prefix_sig + (size_t)cb * SIG13;
    float A1a = P[ia];
    float A2 = P[16 + t];
    V16 A3 = ldv16(P + 272 + t * 16);
    V16 ac0 = zerov16(), ac1 = zerov16(), ac2 = zerov16(), ac3 = zerov16();

    const int s0 = cb * TSTEP;
    const int s1 = (s0 + TSTEP < NSTEP) ? (s0 + TSTEP) : NSTEP;
#pragma unroll 2
    for (int s = s0; s < s1; ++s) {
        const float* row = dx + (size_t)s * DIMV;
        V16 dxv = ldv16(row);
        float dxa = row[ia];
        float dxb = row[ib];
        float4 qd = *reinterpret_cast<const float4*>(row + g * 4);

        float U2 = fmaf(dxb, fmaf(dxa, 1.f/24.f, A1a * (1.f/6.f)), 0.5f * A2);
        float V2 = fmaf(dxb, fmaf(dxa, 1.f/6.f, A1a * 0.5f), A2);
        float h2 = fmaf(dxa, 0.5f, A1a);
#define S4(Q,C) { float u3 = fmaf(dxv.Q.C, U2, A3.Q.C); \
                  ac0.Q.C = fmaf(u3, qd.x, ac0.Q.C); \
                  ac1.Q.C = fmaf(u3, qd.y, ac1.Q.C); \
                  ac2.Q.C = fmaf(u3, qd.z, ac2.Q.C); \
                  ac3.Q.C = fmaf(u3, qd.w, ac3.Q.C); \
                  A3.Q.C = fmaf(dxv.Q.C, V2, A3.Q.C); }
        EACH(S4)
#undef S4
        A2 = fmaf(dxb, h2, A2);
        A1a += dxa;
    }

    if (ATOMIC) {
        float* o = dst + t * 256 + g * 4;
#define STA(J,Q,C) { atomicAdd(o + (J)*16 + 0, ac0.Q.C); atomicAdd(o + (J)*16 + 1, ac1.Q.C); \
                     atomicAdd(o + (J)*16 + 2, ac2.Q.C); atomicAdd(o + (J)*16 + 3, ac3.Q.C); }
        EACHI(STA)
#undef STA
    } else {
        float* o = dst + (size_t)cb * L4 + t * 256 + g * 4;
#define STO(J,Q,C) *reinterpret_cast<float4*>(o + (J)*16) = \
                       make_float4(ac0.Q.C, ac1.Q.C, ac2.Q.C, ac3.Q.C);
        EACHI(STO)
#undef STO
    }
}

// ------------- sum per-chunk level-4 partials (float4) -------------
__global__ __launch_bounds__(256) void k_reduce4(const float* __restrict__ partials,
                                                 float* __restrict__ out4) {
    const int i4 = blockIdx.x * 256 + threadIdx.x;  // 0..16383 float4 slots
    const float4* p4 = reinterpret_cast<const float4*>(partials);
    float4 s = make_float4(0.f, 0.f, 0.f, 0.f);
#pragma unroll 8
    for (int c = 0; c < NC; ++c) {
        float4 v = p4[(size_t)c * (L4 / 4) + i4];
        s.x += v.x; s.y += v.y; s.z += v.z; s.w += v.w;
    }
    reinterpret_cast<float4*>(out4)[i4] = s;
}

extern "C" void kernel_launch(void* const* d_in, const int* in_sizes, int n_in,
                              void* d_out, int out_size, void* d_ws, size_t ws_size,
                              hipStream_t stream) {
    const float* x = (const float*)d_in[0];
    float* out = (float*)d_out;
    float* ws = (float*)d_ws;

    float* dx = ws;                                   // 65536 floats
    float* chunk_sig = ws + 65536;                    // NC * SIG13
    float* prefix_sig = chunk_sig + NC * SIG13;       // NC * SIG13
    float* partials = prefix_sig + NC * SIG13;        // NC * L4
    const size_t need_bytes =
        ((size_t)65536 + 2ull * NC * SIG13 + (size_t)NC * L4) * sizeof(float);

    k_chunk_sig<<<dim3(NC), dim3(256), 0, stream>>>(x, dx, chunk_sig);
    k_prefix12<<<dim3(1), dim3(256), 0, stream>>>(chunk_sig, prefix_sig, out);
    k_prefix3<<<dim3(16), dim3(256), 0, stream>>>(chunk_sig, prefix_sig, out);

    if (ws_size >= need_bytes) {
        k_scan4<false><<<dim3(NC, 4), dim3(256), 0, stream>>>(dx, prefix_sig, partials);
        k_reduce4<<<dim3(64), dim3(256), 0, stream>>>(partials, out + SIG13);
    } else {
        hipMemsetAsync(out + SIG13, 0, (size_t)L4 * sizeof(float), stream);
        k_scan4<true><<<dim3(NC, 4), dim3(256), 0, stream>>>(dx, prefix_sig, out + SIG13);
    }
}

// Round 5
// 89.862 us; speedup vs baseline: 1.1210x; 1.1210x over previous
//
#include <hip/hip_runtime.h>

#define DIMV 16
#define NSTEP 4095      // 4096 - 1 increments
#define NC 128          // fine chunks (levels 1-3 pipeline)
#define TSTEP 32        // fine chunk length
#define NC4 64          // coarse chunks for level-4 scan (= 2 fine chunks)
#define T4 64           // coarse chunk length
#define SIG13 4368      // 16 + 256 + 4096
#define L4 65536        // 16^4

// 16-wide register vector as 4 explicit float4s — never runtime-indexed (rule #20).
struct V16 { float4 a, b, c, d; };

#define EACH(OP) OP(a,x) OP(a,y) OP(a,z) OP(a,w) OP(b,x) OP(b,y) OP(b,z) OP(b,w) \
                 OP(c,x) OP(c,y) OP(c,z) OP(c,w) OP(d,x) OP(d,y) OP(d,z) OP(d,w)

__device__ inline V16 ldv16(const float* p) {
    const float4* q = reinterpret_cast<const float4*>(p);
    V16 v; v.a = q[0]; v.b = q[1]; v.c = q[2]; v.d = q[3]; return v;
}
__device__ inline void stv16(float* p, const V16& v) {
    float4* q = reinterpret_cast<float4*>(p);
    q[0] = v.a; q[1] = v.b; q[2] = v.c; q[3] = v.d;
}
__device__ inline V16 zerov16() {
    V16 v; v.a = v.b = v.c = v.d = make_float4(0.f, 0.f, 0.f, 0.f); return v;
}

// ------------- per-chunk LOCAL signature (levels 1-3) + fused dx -------------
__global__ __launch_bounds__(256, 1) void k_chunk_sig(const float* __restrict__ x,
                                                      float* __restrict__ dx,
                                                      float* __restrict__ chunk_sig) {
    const int cb = blockIdx.x;
    const int t = threadIdx.x;
    const int ia = t >> 4, ib = t & 15;
    float A1a = 0.f, A2 = 0.f;
    V16 A3 = zerov16();

    const int s0 = cb * TSTEP;
    const int s1 = (s0 + TSTEP < NSTEP) ? (s0 + TSTEP) : NSTEP;

    V16 xprev = ldv16(x + (size_t)s0 * DIMV);
    float xpa = x[(size_t)s0 * DIMV + ia];
    float xpb = x[(size_t)s0 * DIMV + ib];

    for (int s = s0; s < s1; ++s) {
        const float* nrow = x + (size_t)(s + 1) * DIMV;
        V16 xcur = ldv16(nrow);
        float xca = nrow[ia];
        float xcb = nrow[ib];
        V16 dxv;
#define SB(Q,C) dxv.Q.C = xcur.Q.C - xprev.Q.C;
        EACH(SB)
#undef SB
        float dxa = xca - xpa;
        float dxb = xcb - xpb;
        stv16(dx + (size_t)s * DIMV, dxv);

        float V2 = fmaf(dxb, fmaf(dxa, 1.f/6.f, 0.5f * A1a), A2);
        float h2 = fmaf(dxa, 0.5f, A1a);
#define CS(Q,C) A3.Q.C = fmaf(dxv.Q.C, V2, A3.Q.C);
        EACH(CS)
#undef CS
        A2 = fmaf(dxb, h2, A2);
        A1a += dxa;

        xprev = xcur; xpa = xca; xpb = xcb;
    }
    float* o = chunk_sig + (size_t)cb * SIG13;
    if (ib == 0) o[ia] = A1a;
    o[16 + t] = A2;
    stv16(o + 272 + t * 16, A3);
}

// ------------- parallel cascaded prefix: levels 1 & 2 -------------
__global__ __launch_bounds__(256, 1) void k_prefix12(const float* __restrict__ chunk_sig,
                                                     float* __restrict__ prefix_sig,
                                                     float* __restrict__ out13) {
    __shared__ float s1[NC][16];
    __shared__ float p1[NC][16];
    const int t = threadIdx.x;
#pragma unroll
    for (int base = 0; base < NC; base += 16) {
        int c = base + (t >> 4);
        s1[c][t & 15] = chunk_sig[(size_t)c * SIG13 + (t & 15)];
    }
    __syncthreads();
    if (t < 16) {
        float p = 0.f;
        for (int c = 0; c < NC; ++c) {
            p1[c][t] = p;
            prefix_sig[(size_t)c * SIG13 + t] = p;
            p += s1[c][t];
        }
        out13[t] = p;
    }
    __syncthreads();
    const int a = t >> 4, b = t & 15;
    float pl0 = chunk_sig[0ul * SIG13 + 16 + t];
    float pl1 = chunk_sig[1ul * SIG13 + 16 + t];
    float pl2 = chunk_sig[2ul * SIG13 + 16 + t];
    float pl3 = chunk_sig[3ul * SIG13 + 16 + t];
    float pl4 = chunk_sig[4ul * SIG13 + 16 + t];
    float pl5 = chunk_sig[5ul * SIG13 + 16 + t];
    float pl6 = chunk_sig[6ul * SIG13 + 16 + t];
    float pl7 = chunk_sig[7ul * SIG13 + 16 + t];
    float p = 0.f;
    for (int cb = 0; cb < NC; cb += 8) {
#define STEP2(J) { int c = cb + J; \
        prefix_sig[(size_t)c * SIG13 + 16 + t] = p; \
        p = fmaf(p1[c][a], s1[c][b], p + pl##J); \
        int cn = c + 8; \
        if (cn < NC) pl##J = chunk_sig[(size_t)cn * SIG13 + 16 + t]; }
        STEP2(0) STEP2(1) STEP2(2) STEP2(3) STEP2(4) STEP2(5) STEP2(6) STEP2(7)
#undef STEP2
    }
    out13[16 + t] = p;
}

// ------------- parallel prefix: level 3 -------------
__global__ __launch_bounds__(256, 1) void k_prefix3(const float* __restrict__ chunk_sig,
                                                    float* __restrict__ prefix_sig,
                                                    float* __restrict__ out13) {
    const int a = blockIdx.x;
    const int t = threadIdx.x;
    const int c3 = t & 15;
    const size_t off3 = 272 + (size_t)a * 256 + t;
#define LOADC(J, C) \
    float l3_##J = chunk_sig[(size_t)(C) * SIG13 + off3]; \
    float l2_##J = chunk_sig[(size_t)(C) * SIG13 + 16 + t]; \
    float s1_##J = chunk_sig[(size_t)(C) * SIG13 + c3]; \
    float pa_##J = prefix_sig[(size_t)(C) * SIG13 + a]; \
    float pb_##J = prefix_sig[(size_t)(C) * SIG13 + 16 + (a << 4) + (t >> 4)];
#define RELOADC(J, C) { int cc = (C); if (cc < NC) { \
    l3_##J = chunk_sig[(size_t)cc * SIG13 + off3]; \
    l2_##J = chunk_sig[(size_t)cc * SIG13 + 16 + t]; \
    s1_##J = chunk_sig[(size_t)cc * SIG13 + c3]; \
    pa_##J = prefix_sig[(size_t)cc * SIG13 + a]; \
    pb_##J = prefix_sig[(size_t)cc * SIG13 + 16 + (a << 4) + (t >> 4)]; } }
    LOADC(0, 0) LOADC(1, 1) LOADC(2, 2) LOADC(3, 3)
    float p = 0.f;
    for (int cb = 0; cb < NC; cb += 4) {
#define STEP3(J) { int c = cb + J; \
        prefix_sig[(size_t)c * SIG13 + off3] = p; \
        p = p + l3_##J + fmaf(pa_##J, l2_##J, pb_##J * s1_##J); \
        RELOADC(J, c + 4) }
        STEP3(0) STEP3(1) STEP3(2) STEP3(3)
#undef STEP3
    }
    out13[off3] = p;
#undef LOADC
#undef RELOADC
}

// ------------- level-4 accumulation: j-pair split -------------
// block (cb, h): coarse chunk cb (64 steps), j-pair h (j = 2h, 2h+1).
// Per-thread state: A1a, A2 (shared recurrence), A3 pair, acc[2][16].
// VGPR ~70-90 -> 2 blocks/CU at __launch_bounds__(256,2) with NO spill.
template <bool ATOMIC>
__global__ __launch_bounds__(256, 2) void k_scan4(const float* __restrict__ dx,
                                                  const float* __restrict__ prefix_sig,
                                                  float* __restrict__ dst) {
    const int cb = blockIdx.x;   // 0..NC4-1
    const int h = blockIdx.y;    // 0..7 : j-pair
    const int t = threadIdx.x;
    const int ia = t >> 4, ib = t & 15;

    const float* P = prefix_sig + (size_t)(2 * cb) * SIG13;  // coarse chunk = fine chunk 2cb
    float A1a = P[ia];
    float A2 = P[16 + t];
    float2 A3p = *reinterpret_cast<const float2*>(P + 272 + t * 16 + h * 2);
    V16 ac0 = zerov16(), ac1 = zerov16();

    const int s0 = cb * T4;
    const int s1 = (s0 + T4 < NSTEP) ? (s0 + T4) : NSTEP;
    for (int s = s0; s < s1; ++s) {
        const float* row = dx + (size_t)s * DIMV;
        V16 dxv = ldv16(row);
        float dxa = row[ia];
        float dxb = row[ib];
        float2 dj = *reinterpret_cast<const float2*>(row + h * 2);

        float U2 = fmaf(dxb, fmaf(dxa, 1.f/24.f, A1a * (1.f/6.f)), 0.5f * A2);
        float V2 = fmaf(dxb, fmaf(dxa, 1.f/6.f, A1a * 0.5f), A2);
        float h2 = fmaf(dxa, 0.5f, A1a);
        float u30 = fmaf(dj.x, U2, A3p.x);
        float u31 = fmaf(dj.y, U2, A3p.y);
#define AC(Q,C) { ac0.Q.C = fmaf(u30, dxv.Q.C, ac0.Q.C); \
                  ac1.Q.C = fmaf(u31, dxv.Q.C, ac1.Q.C); }
        EACH(AC)
#undef AC
        A3p.x = fmaf(dj.x, V2, A3p.x);
        A3p.y = fmaf(dj.y, V2, A3p.y);
        A2 = fmaf(dxb, h2, A2);
        A1a += dxa;
    }

    // output element (a,b,j,d) at t*256 + j*16 + d
    if (ATOMIC) {
        float* o = dst + t * 256 + (h * 2) * 16;
#define STA(Q,C,K) atomicAdd(o + (K), ac0.Q.C); atomicAdd(o + 16 + (K), ac1.Q.C);
        STA(a,x,0) STA(a,y,1) STA(a,z,2) STA(a,w,3)
        STA(b,x,4) STA(b,y,5) STA(b,z,6) STA(b,w,7)
        STA(c,x,8) STA(c,y,9) STA(c,z,10) STA(c,w,11)
        STA(d,x,12) STA(d,y,13) STA(d,z,14) STA(d,w,15)
#undef STA
    } else {
        float* o = dst + (size_t)cb * L4 + t * 256 + (h * 2) * 16;
        stv16(o, ac0);
        stv16(o + 16, ac1);
    }
}

// ------------- sum per-chunk level-4 partials (float4) -------------
__global__ __launch_bounds__(256) void k_reduce4(const float* __restrict__ partials,
                                                 float* __restrict__ out4) {
    const int i4 = blockIdx.x * 256 + threadIdx.x;  // 0..16383 float4 slots
    const float4* p4 = reinterpret_cast<const float4*>(partials);
    float4 s = make_float4(0.f, 0.f, 0.f, 0.f);
#pragma unroll 8
    for (int c = 0; c < NC4; ++c) {
        float4 v = p4[(size_t)c * (L4 / 4) + i4];
        s.x += v.x; s.y += v.y; s.z += v.z; s.w += v.w;
    }
    reinterpret_cast<float4*>(out4)[i4] = s;
}

extern "C" void kernel_launch(void* const* d_in, const int* in_sizes, int n_in,
                              void* d_out, int out_size, void* d_ws, size_t ws_size,
                              hipStream_t stream) {
    const float* x = (const float*)d_in[0];
    float* out = (float*)d_out;
    float* ws = (float*)d_ws;

    float* dx = ws;                                   // 65536 floats
    float* chunk_sig = ws + 65536;                    // NC * SIG13
    float* prefix_sig = chunk_sig + NC * SIG13;       // NC * SIG13
    float* partials = prefix_sig + NC * SIG13;        // NC4 * L4
    const size_t need_bytes =
        ((size_t)65536 + 2ull * NC * SIG13 + (size_t)NC4 * L4) * sizeof(float);

    k_chunk_sig<<<dim3(NC), dim3(256), 0, stream>>>(x, dx, chunk_sig);
    k_prefix12<<<dim3(1), dim3(256), 0, stream>>>(chunk_sig, prefix_sig, out);
    k_prefix3<<<dim3(16), dim3(256), 0, stream>>>(chunk_sig, prefix_sig, out);

    if (ws_size >= need_bytes) {
        k_scan4<false><<<dim3(NC4, 8), dim3(256), 0, stream>>>(dx, prefix_sig, partials);
        k_reduce4<<<dim3(64), dim3(256), 0, stream>>>(partials, out + SIG13);
    } else {
        hipMemsetAsync(out + SIG13, 0, (size_t)L4 * sizeof(float), stream);
        k_scan4<true><<<dim3(NC4, 8), dim3(256), 0, stream>>>(dx, prefix_sig, out + SIG13);
    }
}